// Round 3
// baseline (789.360 us; speedup 1.0000x reference)
//
#include <hip/hip_runtime.h>
#include <hip/hip_bf16.h>

#define NN 32768
#define KK 1024
#define DD 256
#define RB 8            // rows per block
#define CTILE 128       // prototype-column tile
#define DTILE 32        // d tile for P staging
#define PS_STRIDE 36    // 128 rows x (32+4) floats: 16B-aligned rows, conflict-spread
#define XS_STRIDE 260   // 256+4 floats, 16B-aligned rows

// ws layout (floats): [0,1024) np2 | [1024,2048) colsum_y | [2048,3072) colsum_lp

__global__ void vq_init(const float* __restrict__ protos, float* __restrict__ ws) {
    int t = threadIdx.x;  // one block of 256, 4 protos per thread
    for (int i = 0; i < 4; ++i) {
        int k = t + i * 256;
        const float4* p4 = reinterpret_cast<const float4*>(protos + (size_t)k * DD);
        float s = 0.f;
#pragma unroll 8
        for (int j = 0; j < DD / 4; ++j) {
            float4 v = p4[j];
            s = fmaf(v.x, v.x, s); s = fmaf(v.y, v.y, s);
            s = fmaf(v.z, v.z, s); s = fmaf(v.w, v.w, s);
        }
        ws[k] = s;
        ws[KK + k] = 0.f;
        ws[2 * KK + k] = 0.f;
    }
}

__global__ void __launch_bounds__(256)
VQLayer_21586505630024_kernel(const float* __restrict__ latents,
                              const float* __restrict__ protos,
                              const float* __restrict__ gumbel,
                              float* __restrict__ ws,
                              float* __restrict__ out) {
    __shared__ float Xs[RB][XS_STRIDE];
    __shared__ float Ss[RB][KK];
    __shared__ float Ps[CTILE][PS_STRIDE];
    __shared__ float rowlz[RB];
    __shared__ int rowidx[RB];

    const int t = threadIdx.x;
    const int n0 = blockIdx.x * RB;
    const float* np2 = ws;
    float* colsum_y = ws + KK;
    float* colsum_lp = ws + 2 * KK;

    // ---- stage X tile: 8 rows x 256 floats = 512 float4, 2 per thread ----
#pragma unroll
    for (int i = 0; i < 2; ++i) {
        int g = t + i * 256;          // 0..511
        int r = g >> 6;
        int dc = (g & 63) << 2;
        float4 v = *reinterpret_cast<const float4*>(latents + (size_t)(n0 + r) * DD + dc);
        Xs[r][dc] = v.x; Xs[r][dc + 1] = v.y; Xs[r][dc + 2] = v.z; Xs[r][dc + 3] = v.w;
    }

    const int lane = t & 63;
    const int wv = t >> 6;            // wave id 0..3
    const int c0 = lane;              // column within tile (also +64)
    const int r0 = wv * 2;            // two rows per wave

    // ---- GEMM: logits tile [8][1024] into LDS ----
    for (int ct = 0; ct < KK / CTILE; ++ct) {
        float a00 = 0.f, a01 = 0.f, a10 = 0.f, a11 = 0.f;
        for (int dt = 0; dt < DD / DTILE; ++dt) {
            __syncthreads();  // Ps readers from prev iter done (also covers Xs stage 1st time)
            // stage Ps[128][32]: 1024 float4, 4 per thread
#pragma unroll
            for (int i = 0; i < 4; ++i) {
                int g = t + i * 256;       // 0..1023
                int pr = g >> 3;           // 8 float4 per proto row
                int pdc = (g & 7) << 2;
                float4 v = *reinterpret_cast<const float4*>(
                    protos + (size_t)(ct * CTILE + pr) * DD + dt * DTILE + pdc);
                Ps[pr][pdc] = v.x; Ps[pr][pdc + 1] = v.y; Ps[pr][pdc + 2] = v.z; Ps[pr][pdc + 3] = v.w;
            }
            __syncthreads();
#pragma unroll
            for (int d4 = 0; d4 < DTILE / 4; ++d4) {
                int d = d4 * 4;
                float4 p0 = *reinterpret_cast<const float4*>(&Ps[c0][d]);
                float4 p1 = *reinterpret_cast<const float4*>(&Ps[c0 + 64][d]);
                int dd = dt * DTILE + d;
                float4 x0 = *reinterpret_cast<const float4*>(&Xs[r0][dd]);
                float4 x1 = *reinterpret_cast<const float4*>(&Xs[r0 + 1][dd]);
                a00 = fmaf(x0.x, p0.x, a00); a00 = fmaf(x0.y, p0.y, a00);
                a00 = fmaf(x0.z, p0.z, a00); a00 = fmaf(x0.w, p0.w, a00);
                a01 = fmaf(x0.x, p1.x, a01); a01 = fmaf(x0.y, p1.y, a01);
                a01 = fmaf(x0.z, p1.z, a01); a01 = fmaf(x0.w, p1.w, a01);
                a10 = fmaf(x1.x, p0.x, a10); a10 = fmaf(x1.y, p0.y, a10);
                a10 = fmaf(x1.z, p0.z, a10); a10 = fmaf(x1.w, p0.w, a10);
                a11 = fmaf(x1.x, p1.x, a11); a11 = fmaf(x1.y, p1.y, a11);
                a11 = fmaf(x1.z, p1.z, a11); a11 = fmaf(x1.w, p1.w, a11);
            }
        }
        // write logits (row-constant -||x||^2 dropped: cancels in softmax/argmax)
        int k0 = ct * CTILE + c0;
        int k1 = k0 + 64;
        float g00 = gumbel[(size_t)(n0 + r0) * KK + k0];
        float g01 = gumbel[(size_t)(n0 + r0) * KK + k1];
        float g10 = gumbel[(size_t)(n0 + r0 + 1) * KK + k0];
        float g11 = gumbel[(size_t)(n0 + r0 + 1) * KK + k1];
        float q0 = np2[k0], q1 = np2[k1];
        Ss[r0][k0]     = fmaf(2.f, a00, -q0) + g00;
        Ss[r0][k1]     = fmaf(2.f, a01, -q1) + g01;
        Ss[r0 + 1][k0] = fmaf(2.f, a10, -q0) + g10;
        Ss[r0 + 1][k1] = fmaf(2.f, a11, -q1) + g11;
    }
    __syncthreads();

    // ---- per-row softmax stats: each wave owns rows r0, r0+1 ----
#pragma unroll
    for (int rr = 0; rr < 2; ++rr) {
        int r = r0 + rr;
        float vmax = -3.4e38f; int imax = 0;
#pragma unroll
        for (int j = 0; j < KK / 64; ++j) {
            int k = lane + j * 64;
            float v = Ss[r][k];
            if (v > vmax) { vmax = v; imax = k; }
        }
#pragma unroll
        for (int off = 32; off >= 1; off >>= 1) {
            float ov = __shfl_xor(vmax, off);
            int   oi = __shfl_xor(imax, off);
            if (ov > vmax || (ov == vmax && oi < imax)) { vmax = ov; imax = oi; }
        }
        float se = 0.f;
#pragma unroll
        for (int j = 0; j < KK / 64; ++j)
            se += __expf(Ss[r][lane + j * 64] - vmax);
#pragma unroll
        for (int off = 32; off >= 1; off >>= 1) se += __shfl_xor(se, off);
        if (lane == 0) { rowlz[r] = vmax + __logf(se); rowidx[r] = imax; }
    }
    __syncthreads();

    // ---- column partial sums of y_soft and logprobs -> global atomics ----
    float lz[RB];
#pragma unroll
    for (int r = 0; r < RB; ++r) lz[r] = rowlz[r];
#pragma unroll
    for (int j = 0; j < 4; ++j) {
        int c = t + j * 256;
        float sy = 0.f, slp = 0.f;
#pragma unroll
        for (int r = 0; r < RB; ++r) {
            float lp = Ss[r][c] - lz[r];
            slp += lp;
            sy += __expf(lp);
        }
        atomicAdd(&colsum_y[c], sy);
        atomicAdd(&colsum_lp[c], slp);
    }

    // ---- quantized = protos[argmax] as f32: thread t -> row t>>5, 8 elems ----
    {
        int r = t >> 5;
        int d0 = (t & 31) * 8;
        int idx = rowidx[r];
        const float4* p4 = reinterpret_cast<const float4*>(protos + (size_t)idx * DD + d0);
        float4 a = p4[0], b = p4[1];
        float4* o = reinterpret_cast<float4*>(out + (size_t)(n0 + r) * DD + d0);
        o[0] = a;
        o[1] = b;
    }
}

__global__ void vq_final(const float* __restrict__ ws,
                         float* __restrict__ out, int out_size) {
    __shared__ float part[4];
    int t = threadIdx.x;  // one block of 256
    const float invN = 1.0f / (float)NN;
    float a = 0.f;
    for (int j = 0; j < 4; ++j) {
        int k = t + j * 256;
        float prior = fmaf(ws[KK + k], invN, 1e-6f);
        float Lk = ws[2 * KK + k] * invN;
        a += prior * (1.001f * __logf(prior) - Lk);
    }
#pragma unroll
    for (int off = 32; off >= 1; off >>= 1) a += __shfl_xor(a, off);
    if ((t & 63) == 0) part[t >> 6] = a;
    __syncthreads();
    if (t == 0) {
        float v = part[0] + part[1] + part[2] + part[3];
        out[out_size - 1] = v;
    }
}

extern "C" void kernel_launch(void* const* d_in, const int* in_sizes, int n_in,
                              void* d_out, int out_size, void* d_ws, size_t ws_size,
                              hipStream_t stream) {
    (void)in_sizes; (void)n_in; (void)ws_size;
    const float* latents = (const float*)d_in[0];
    const float* protos  = (const float*)d_in[1];
    const float* gumbel  = (const float*)d_in[2];
    float* out           = (float*)d_out;
    float* ws            = (float*)d_ws;

    vq_init<<<dim3(1), dim3(256), 0, stream>>>(protos, ws);
    VQLayer_21586505630024_kernel<<<dim3(NN / RB), dim3(256), 0, stream>>>(
        latents, protos, gumbel, ws, out);
    vq_final<<<dim3(1), dim3(256), 0, stream>>>(ws, out, out_size);
}

// Round 4
// 141.910 us; speedup vs baseline: 5.5624x; 5.5624x over previous
//
#include <hip/hip_runtime.h>
#include <hip/hip_bf16.h>
#include <stdint.h>

#define NN 32768
#define KK 1024
#define DD 256
#define BM 32
#define CHUNK 128
#define NCHUNK (KK / CHUNK)   // 8
#define NTHR 512

// LDS byte offsets (total 147712 B < 163840)
#define LXS 0                   // Xs: 32 rows * 512B bf16, 16B-granule XOR-swizzled
#define LPS 16384               // Ps: 128 protos * 512B bf16, 16B-granule XOR-swizzled
#define LSS (LPS + 65536)       // Ss: 32 rows * 2048B bf16, 8B-granule XOR-swizzled
#define LRM (LSS + 65536)       // row logZ f32[32]
#define LRI (LRM + 128)         // row argmax i32[32]
#define LTOT (LRI + 128)

// ws layout (floats): [0,1024) np2 | [1024,2048) colsum_y | [2048,3072) colsum_lp
// | bytes [12288, 12288+524288) Pbf16 (fast path)

typedef __attribute__((ext_vector_type(8))) short bf16x8;
typedef __attribute__((ext_vector_type(4))) float f32x4;

__device__ __forceinline__ uint32_t pkbf2(float a, float b) {  // RNE f32->bf16 pack
    uint32_t ua = __builtin_bit_cast(uint32_t, a);
    uint32_t ub = __builtin_bit_cast(uint32_t, b);
    ua = (ua + 0x7fffu + ((ua >> 16) & 1u)) >> 16;
    ub = (ub + 0x7fffu + ((ub >> 16) & 1u)) >> 16;
    return ua | (ub << 16);
}
__device__ __forceinline__ float ubf(uint32_t h) {  // bf16 bits -> f32 (exact)
    return __builtin_bit_cast(float, h << 16);
}

__global__ void vq_init(const float* __restrict__ protos, float* __restrict__ ws) {
    int t = threadIdx.x;  // 1 block x 256
    for (int i = 0; i < 4; ++i) {
        int k = t + i * 256;
        const float4* p4 = reinterpret_cast<const float4*>(protos + (size_t)k * DD);
        float s = 0.f;
#pragma unroll 8
        for (int j = 0; j < DD / 4; ++j) {
            float4 v = p4[j];
            s = fmaf(v.x, v.x, s); s = fmaf(v.y, v.y, s);
            s = fmaf(v.z, v.z, s); s = fmaf(v.w, v.w, s);
        }
        ws[k] = s;
        ws[KK + k] = 0.f;
        ws[2 * KK + k] = 0.f;
    }
}

__global__ void vq_cvt(const float* __restrict__ protos, uint32_t* __restrict__ pb) {
    int idx = blockIdx.x * 256 + threadIdx.x;  // 0..32767, 8 floats each
    const float4* s = reinterpret_cast<const float4*>(protos + (size_t)idx * 8);
    float4 a = s[0], b = s[1];
    uint4 v;
    v.x = pkbf2(a.x, a.y); v.y = pkbf2(a.z, a.w);
    v.z = pkbf2(b.x, b.y); v.w = pkbf2(b.z, b.w);
    reinterpret_cast<uint4*>(pb)[idx] = v;
}

template<bool PRE>
__global__ __launch_bounds__(NTHR) void vq_mainT(const float* __restrict__ latents,
                                                 const float* __restrict__ protos,
                                                 const float* __restrict__ gumbel,
                                                 float* __restrict__ ws,
                                                 float* __restrict__ out) {
    __shared__ __align__(16) unsigned char sm[LTOT];
    const int t = threadIdx.x;
    const int lane = t & 63;
    const int w = t >> 6;                 // wave 0..7
    const int n0 = blockIdx.x * BM;
    const float* np2 = ws;
    float* colsum_y = ws + KK;
    float* colsum_lp = ws + 2 * KK;
    const uint4* pb = reinterpret_cast<const uint4*>(ws + 3 * KK);

    // ---- stage X: 32 rows x 256 f32 -> bf16 LDS (swizzled) ----
    {
        int row = t >> 4;
        int g0 = (t & 15) * 2;
#pragma unroll
        for (int j = 0; j < 2; ++j) {
            int g = g0 + j;
            const float4* src = reinterpret_cast<const float4*>(
                latents + (size_t)(n0 + row) * DD + g * 8);
            float4 a = src[0], b = src[1];
            uint4 v; v.x = pkbf2(a.x, a.y); v.y = pkbf2(a.z, a.w);
            v.z = pkbf2(b.x, b.y); v.w = pkbf2(b.z, b.w);
            *reinterpret_cast<uint4*>(sm + LXS + row * 512 + ((g ^ (row & 7)) << 4)) = v;
        }
    }

    const int l15 = lane & 15;
    const int l4 = lane >> 4;
    const int pr = w * 16 + l15;          // proto row (local) for A-frag

    for (int c = 0; c < NCHUNK; ++c) {
        __syncthreads();                  // prev chunk Ps reads done / Xs visible
        // ---- stage Ps: 128 protos x 256 bf16 ----
        if (PRE) {
#pragma unroll
            for (int i = 0; i < 8; ++i) {
                int G = t + NTHR * i;     // 16B-granule id, 0..4095
                int p = G >> 5, g = G & 31;
                uint4 v = pb[(size_t)(c * CHUNK + p) * 32 + g];
                *reinterpret_cast<uint4*>(sm + LPS + p * 512 + ((g ^ (p & 7)) << 4)) = v;
            }
        } else {
#pragma unroll
            for (int i = 0; i < 8; ++i) {
                int G = t + NTHR * i;
                int p = G >> 5, g = G & 31;
                const float4* src = reinterpret_cast<const float4*>(
                    protos + (size_t)(c * CHUNK + p) * DD + g * 8);
                float4 a = src[0], b = src[1];
                uint4 v; v.x = pkbf2(a.x, a.y); v.y = pkbf2(a.z, a.w);
                v.z = pkbf2(b.x, b.y); v.w = pkbf2(b.z, b.w);
                *reinterpret_cast<uint4*>(sm + LPS + p * 512 + ((g ^ (p & 7)) << 4)) = v;
            }
        }
        __syncthreads();

        // prefetch epilogue operands (hide HBM latency under MFMA)
        const int pg0 = c * CHUNK + w * 16 + l4 * 4;   // proto global base for regs 0..3
        float4 q4 = *reinterpret_cast<const float4*>(np2 + pg0);
        float4 g40 = *reinterpret_cast<const float4*>(gumbel + (size_t)(n0 + l15) * KK + pg0);
        float4 g41 = *reinterpret_cast<const float4*>(gumbel + (size_t)(n0 + 16 + l15) * KK + pg0);

        f32x4 acc0 = {0.f, 0.f, 0.f, 0.f}, acc1 = {0.f, 0.f, 0.f, 0.f};
#pragma unroll
        for (int ks = 0; ks < 8; ++ks) {
            int gi = ks * 4 + l4;
            bf16x8 af = *reinterpret_cast<bf16x8*>(sm + LPS + pr * 512 + ((gi ^ (pr & 7)) << 4));
            bf16x8 b0 = *reinterpret_cast<bf16x8*>(sm + LXS + l15 * 512 + ((gi ^ (l15 & 7)) << 4));
            bf16x8 b1 = *reinterpret_cast<bf16x8*>(sm + LXS + (16 + l15) * 512 + ((gi ^ ((16 + l15) & 7)) << 4));
            acc0 = __builtin_amdgcn_mfma_f32_16x16x32_bf16(af, b0, acc0, 0, 0, 0);
            acc1 = __builtin_amdgcn_mfma_f32_16x16x32_bf16(af, b1, acc1, 0, 0, 0);
        }
        // ---- epilogue: S = 2*acc - np2 + gumbel -> bf16 Ss (swizzled b64 writes) ----
        const int Gs = pg0 >> 2;          // 8B-granule index within row
        {
            int xrow = l15;
            uint2 pk;
            pk.x = pkbf2(fmaf(2.f, acc0.x, -q4.x) + g40.x, fmaf(2.f, acc0.y, -q4.y) + g40.y);
            pk.y = pkbf2(fmaf(2.f, acc0.z, -q4.z) + g40.z, fmaf(2.f, acc0.w, -q4.w) + g40.w);
            *reinterpret_cast<uint2*>(sm + LSS + xrow * 2048 + ((Gs ^ ((xrow & 7) << 1)) << 3)) = pk;
        }
        {
            int xrow = 16 + l15;
            uint2 pk;
            pk.x = pkbf2(fmaf(2.f, acc1.x, -q4.x) + g41.x, fmaf(2.f, acc1.y, -q4.y) + g41.y);
            pk.y = pkbf2(fmaf(2.f, acc1.z, -q4.z) + g41.z, fmaf(2.f, acc1.w, -q4.w) + g41.w);
            *reinterpret_cast<uint2*>(sm + LSS + xrow * 2048 + ((Gs ^ ((xrow & 7) << 1)) << 3)) = pk;
        }
    }
    __syncthreads();

    // ---- Phase B: per-row max/argmax/logZ (16 threads per row) ----
    {
        int row = t >> 4, v = t & 15;
        int sw = (row & 7) << 1;
        uint2 d[16];
#pragma unroll
        for (int j = 0; j < 16; ++j) {
            int G = v + 16 * j;
            d[j] = *reinterpret_cast<uint2*>(sm + LSS + row * 2048 + ((G ^ sw) << 3));
        }
        float m = -3.4e38f; int mi = 0;
#pragma unroll
        for (int j = 0; j < 16; ++j) {
            int c0 = (v + 16 * j) * 4;
            float f0 = ubf(d[j].x & 0xffffu), f1 = ubf(d[j].x >> 16);
            float f2 = ubf(d[j].y & 0xffffu), f3 = ubf(d[j].y >> 16);
            if (f0 > m) { m = f0; mi = c0; }
            if (f1 > m) { m = f1; mi = c0 + 1; }
            if (f2 > m) { m = f2; mi = c0 + 2; }
            if (f3 > m) { m = f3; mi = c0 + 3; }
        }
#pragma unroll
        for (int off = 1; off < 16; off <<= 1) {
            float om = __shfl_xor(m, off);
            int oi = __shfl_xor(mi, off);
            if (om > m || (om == m && oi < mi)) { m = om; mi = oi; }
        }
        float se = 0.f;
#pragma unroll
        for (int j = 0; j < 16; ++j) {
            se += __expf(ubf(d[j].x & 0xffffu) - m);
            se += __expf(ubf(d[j].x >> 16) - m);
            se += __expf(ubf(d[j].y & 0xffffu) - m);
            se += __expf(ubf(d[j].y >> 16) - m);
        }
#pragma unroll
        for (int off = 1; off < 16; off <<= 1) se += __shfl_xor(se, off);
        if (v == 0) {
            *reinterpret_cast<float*>(sm + LRM + row * 4) = m + __logf(se);
            *reinterpret_cast<int*>(sm + LRI + row * 4) = mi;
        }
    }
    __syncthreads();

    // ---- Phase C1: column partial sums -> global atomics ----
#pragma unroll
    for (int h = 0; h < 2; ++h) {
        int col = t + h * NTHR;
        int G = col >> 2;
        int e2 = (col & 3) << 1;
        float sy = 0.f, slp = 0.f;
#pragma unroll 8
        for (int r = 0; r < BM; ++r) {
            uint32_t hv = *reinterpret_cast<uint16_t*>(
                sm + LSS + r * 2048 + ((G ^ ((r & 7) << 1)) << 3) + e2);
            float lz = *reinterpret_cast<float*>(sm + LRM + r * 4);
            float lp = ubf(hv) - lz;
            slp += lp;
            sy += __expf(lp);
        }
        atomicAdd(&colsum_y[col], sy);
        atomicAdd(&colsum_lp[col], slp);
    }

    // ---- Phase C2: quantized = protos[argmax] (f32 gather) ----
    {
        int row = t >> 4, v = t & 15;
        int idx = *reinterpret_cast<int*>(sm + LRI + row * 4);
        const float4* src = reinterpret_cast<const float4*>(protos + (size_t)idx * DD + v * 16);
        float4* dst = reinterpret_cast<float4*>(out + (size_t)(n0 + row) * DD + v * 16);
#pragma unroll
        for (int j = 0; j < 4; ++j) dst[j] = src[j];
    }
}

__global__ void vq_final(const float* __restrict__ ws,
                         float* __restrict__ out, int out_size) {
    __shared__ float part[4];
    int t = threadIdx.x;  // 1 block x 256
    const float invN = 1.0f / (float)NN;
    float a = 0.f;
    for (int j = 0; j < 4; ++j) {
        int k = t + j * 256;
        float prior = fmaf(ws[KK + k], invN, 1e-6f);
        float Lk = ws[2 * KK + k] * invN;
        a += prior * (1.001f * __logf(prior) - Lk);
    }
#pragma unroll
    for (int off = 32; off >= 1; off >>= 1) a += __shfl_xor(a, off);
    if ((t & 63) == 0) part[t >> 6] = a;
    __syncthreads();
    if (t == 0) {
        out[out_size - 1] = part[0] + part[1] + part[2] + part[3];
    }
}

extern "C" void kernel_launch(void* const* d_in, const int* in_sizes, int n_in,
                              void* d_out, int out_size, void* d_ws, size_t ws_size,
                              hipStream_t stream) {
    (void)in_sizes; (void)n_in;
    const float* latents = (const float*)d_in[0];
    const float* protos  = (const float*)d_in[1];
    const float* gumbel  = (const float*)d_in[2];
    float* out           = (float*)d_out;
    float* ws            = (float*)d_ws;

    bool pre = ws_size >= (size_t)(3 * KK * 4 + KK * DD * 2);

    vq_init<<<dim3(1), dim3(256), 0, stream>>>(protos, ws);
    if (pre) {
        vq_cvt<<<dim3(KK * DD / 2048), dim3(256), 0, stream>>>(
            protos, (uint32_t*)(ws + 3 * KK));
        vq_mainT<true><<<dim3(NN / BM), dim3(NTHR), 0, stream>>>(
            latents, protos, gumbel, ws, out);
    } else {
        vq_mainT<false><<<dim3(NN / BM), dim3(NTHR), 0, stream>>>(
            latents, protos, gumbel, ws, out);
    }
    vq_final<<<dim3(1), dim3(256), 0, stream>>>(ws, out, out_size);
}